// Round 10
// baseline (56.678 us; speedup 1.0000x reference)
//
#include <hip/hip_runtime.h>
#include <math.h>

// Keep non-contracted float math in all expressions that feed discrete
// decisions (alpha seeds, voxel trunc) — matches numpy/JAX op-for-op.
#pragma clang fp contract(off)

#define SPLIT 13
#define BATCH 8
static constexpr int HH = 200, WW = 200;
static constexpr int NRAY = HH * WW;

__device__ __forceinline__ float alpha_of(float k, float sp, float src, float sdd) {
    return (k * sp - src) / sdd;   // reference: (k*spacing - src)/sdd, mul-sub-div
}

// Traversal pointer at threshold X: first crossing (traversal order) with
// alpha > X. pos: smallest k, result in [0,257]; neg: largest k, in [-1,256].
// Seeded analytically, fixed up with the exact reference divide (ulp-robust).
__device__ __forceinline__ int seed_ptr(float X, float spv, float sr, float sd, bool pos) {
    const float kf = (X * sd + sr) / spv;
    int kk;
    if (pos) {
        kk = (int)floorf(kf) + 1;
        kk = kk < 0 ? 0 : (kk > 257 ? 257 : kk);
        while (kk > 0    && alpha_of((float)(kk-1), spv, sr, sd) >  X) --kk;
        while (kk <= 256 && alpha_of((float)kk,     spv, sr, sd) <= X) ++kk;
    } else {
        kk = (int)ceilf(kf) - 1;
        kk = kk > 256 ? 256 : (kk < -1 ? -1 : kk);
        while (kk < 256 && alpha_of((float)(kk+1), spv, sr, sd) >  X) ++kk;
        while (kk >= 0  && alpha_of((float)kk,     spv, sr, sd) <= X) --kk;
    }
    return kk;
}

// Generate one interval's (step, addr) from the tM recurrence and advance.
// Identical float ops to the round-8/9 passing kernels (bit-identical stream).
#define GEN_INTERVAL(stepv, addrv)                                       \
    {   const float q = fminf(fminf(tM0, tM1), tM2);                     \
        stepv = q - prev;                                                \
        const float amid = 0.5f * (prev + q);                            \
        const float p0 = src0 + amid * sdd0;                             \
        const float p1 = src1 + amid * sdd1;                             \
        const float p2 = src2 + amid * sdd2;                             \
        float f0, f1, f2;                                                \
        if (UNIT) { f0 = p0; f1 = p1; f2 = p2; }                         \
        else      { f0 = p0 / spn0; f1 = p1 / spn1; f2 = p2 / spn2; }    \
        f0 = fminf(fmaxf(f0, 0.0f), 255.0f);                             \
        f1 = fminf(fmaxf(f1, 0.0f), 255.0f);                             \
        f2 = fminf(fmaxf(f2, 0.0f), 255.0f);                             \
        const int i0 = (int)f0, i1 = (int)f1, i2 = (int)f2;              \
        addrv = ((((255 ^ i0) << 8) + i1) << 8) + i2;                    \
        prev = q;                                                        \
        const bool m0 = (tM0 == q);                                      \
        const bool m1 = !m0 && (tM1 == q);                               \
        const bool m2 = !(m0 || m1);                                     \
        tM0 = m0 ? tM0 + dl0 : tM0;                                      \
        tM1 = m1 ? tM1 + dl1 : tM1;                                      \
        tM2 = m2 ? tM2 + dl2 : tM2; }

// Generate a full batch (8 addrs) and issue its 8 independent loads.
#define GENB(S, V, A)                                                    \
    _Pragma("unroll")                                                    \
    for (int i = 0; i < BATCH; ++i) {                                    \
        GEN_INTERVAL(S[i], A[i])                                         \
        V[i] = vol[A[i]];                                                \
    }

// Consume a batch in interval order (accumulation order = unbatched loop).
#define CONSB(S, V)                                                      \
    _Pragma("unroll")                                                    \
    for (int i = 0; i < BATCH; ++i)                                      \
        acc = fmaf(S[i], V[i], acc);

// Count-based merge, software-pipelined 2 batches deep: batch k+1's loads are
// issued BEFORE batch k is consumed (program order), so >=8-16 loads stay in
// flight regardless of scheduler conservatism.
template<bool UNIT>
__device__ __forceinline__ float merge_loop(
    const float* __restrict__ vol, int trip, float prev,
    float tM0, float tM1, float tM2,
    float dl0, float dl1, float dl2,
    float src0, float src1, float src2,
    float spn0, float spn1, float spn2,
    float sdd0, float sdd1, float sdd2)
{
    float acc = 0.0f;
    const int n = trip;
    int done = 0;

    if (n >= BATCH) {
        float s0[BATCH], v0[BATCH], s1[BATCH], v1[BATCH];
        int a0[BATCH], a1[BATCH];
        GENB(s0, v0, a0)
        done = BATCH;
        while (done + 2 * BATCH <= n) {
            GENB(s1, v1, a1)
            CONSB(s0, v0)
            GENB(s0, v0, a0)
            CONSB(s1, v1)
            done += 2 * BATCH;
        }
        if (done + BATCH <= n) {
            GENB(s1, v1, a1)
            CONSB(s0, v0)
            CONSB(s1, v1)
            done += BATCH;
        } else {
            CONSB(s0, v0)
        }
    }
    // serial tail (< BATCH intervals)
    for (int r = done; r < n; ++r) {
        float stepv, vox;
        int addr;
        GEN_INTERVAL(stepv, addr)
        vox = vol[addr];
        acc = fmaf(stepv, vox, acc);
    }
    return acc;
}

__global__ __launch_bounds__(256, 4)   // allow <=128 VGPR: room for in-flight loads
void drr_kernel(const float* __restrict__ vol,
                const float* __restrict__ spacing,
                const float* __restrict__ sdrP,
                const float* __restrict__ thetaP,
                const float* __restrict__ phiP,
                const float* __restrict__ gammaP,
                const float* __restrict__ bxP,
                const float* __restrict__ byP,
                const float* __restrict__ bzP,
                float* __restrict__ out)
{
    const int tid = blockIdx.x * blockDim.x + threadIdx.x;
    if (tid >= NRAY * SPLIT) return;          // pad threads exit
    const int seg = tid / NRAY;               // segment in high bits
    const int rid = tid - seg * NRAY;         // lanes = consecutive rid
    const int it  = rid % HH;                 // it fastest -> coalesced i2
    const int is  = rid / HH;

    const float sdr = sdrP[0];
    const float th = thetaP[0], ph = phiP[0], ga = gammaP[0];
    const float ct = cosf(th), st = sinf(th);
    const float cp = cosf(ph), sp = sinf(ph);
    const float cg = cosf(ga), sg = sinf(ga);

    // rotation = Rz @ Ry @ Rx
    const float rot[3][3] = {
        { ct*cp, ct*sp*sg - st*cg, ct*sp*cg + st*sg },
        { st*cp, st*sp*sg + ct*cg, st*sp*cg - ct*sg },
        { -sp,   cp*sg,            cp*cg            }
    };

    float u[3], v[3], source[3], trans[3], src[3], spn[3];
    trans[0] = bxP[0]; trans[1] = byP[0]; trans[2] = bzP[0];
    for (int a = 0; a < 3; ++a) {
        source[a] = sdr * rot[a][0];
        u[a] = (sdr * rot[a][1]) / sdr;
        v[a] = (sdr * rot[a][2]) / sdr;
        src[a] = source[a] + trans[a];
        spn[a] = spacing[a];
    }

    const float tc = (float)(it - HH/2 + 1) * 2.0f;   // DELX
    const float sc = (float)(is - WW/2 + 1) * 2.0f;   // DELY

    float sdd[3];
    float nrm2 = 0.0f;
    for (int a = 0; a < 3; ++a) {
        float tg = tc * u[a] + sc * v[a];
        tg = tg - source[a];     // + center
        tg = tg + trans[a];
        float dd = (tg - src[a]) + 1e-8f;  // sdd = tgt - src + EPS
        sdd[a] = dd;
        nrm2 = nrm2 + dd * dd;
    }
    const bool unit = (spn[0] == 1.0f) & (spn[1] == 1.0f) & (spn[2] == 1.0f);

    float amin = -INFINITY, amax = INFINITY;
    for (int a = 0; a < 3; ++a) {
        float a0 = (0.0f - src[a]) / sdd[a];
        float a1 = (256.0f * spn[a] - src[a]) / sdd[a];
        amin = fmaxf(amin, fminf(a0, a1));
        amax = fminf(amax, fmaxf(a0, a1));
    }

    float acc = 0.0f;
    if (amax > amin) {
        // Segment window (blo, bhi]; identical boundary arithmetic in all segs
        // of a ray, so the windows partition (amin, amax] exactly.
        const float blo = (seg == 0) ? amin
                        : amin + (amax - amin) * ((float)seg / (float)SPLIT);
        const float bhi = (seg == SPLIT - 1) ? amax
                        : amin + (amax - amin) * ((float)(seg + 1) / (float)SPLIT);

        float tM[3], dl[3];
        float prev = -INFINITY;   // largest in-range alpha <= blo
        int trip = 0;

        for (int a = 0; a < 3; ++a) {
            const float sd = sdd[a], sr = src[a], spv = spn[a];
            const bool pos = sd > 0.0f;
            const int ks = seed_ptr(blo, spv, sr, sd, pos);
            const int ke = seed_ptr(bhi, spv, sr, sd, pos);
            int cnt;
            if (pos) {
                cnt = ke - ks;
                if (ks - 1 >= 0) {
                    const float ap = alpha_of((float)(ks-1), spv, sr, sd);
                    if (ap >= amin && ap > prev) prev = ap;
                }
                tM[a] = (ks <= 256) ? alpha_of((float)ks, spv, sr, sd) : INFINITY;
            } else {
                cnt = ks - ke;
                if (ks + 1 <= 256) {
                    const float ap = alpha_of((float)(ks+1), spv, sr, sd);
                    if (ap >= amin && ap > prev) prev = ap;
                }
                tM[a] = (ks >= 0) ? alpha_of((float)ks, spv, sr, sd) : INFINITY;
            }
            if (cnt < 0) cnt = 0;
            trip += cnt;
            dl[a] = fabsf(spv / sd);   // constant alpha increment per crossing
        }

        if (unit) {
            acc = merge_loop<true >(vol, trip, prev,
                                    tM[0], tM[1], tM[2], dl[0], dl[1], dl[2],
                                    src[0], src[1], src[2],
                                    spn[0], spn[1], spn[2],
                                    sdd[0], sdd[1], sdd[2]);
        } else {
            acc = merge_loop<false>(vol, trip, prev,
                                    tM[0], tM[1], tM[2], dl[0], dl[1], dl[2],
                                    src[0], src[1], src[2],
                                    spn[0], spn[1], spn[2],
                                    sdd[0], sdd[1], sdd[2]);
        }
    }

    atomicAdd(&out[it * WW + is], acc * sqrtf(nrm2));
}

extern "C" void kernel_launch(void* const* d_in, const int* in_sizes, int n_in,
                              void* d_out, int out_size, void* d_ws, size_t ws_size,
                              hipStream_t stream)
{
    const float* vol     = (const float*)d_in[0];
    const float* spacing = (const float*)d_in[1];
    const float* sdr     = (const float*)d_in[2];
    const float* theta   = (const float*)d_in[3];
    const float* phi     = (const float*)d_in[4];
    const float* gamma   = (const float*)d_in[5];
    const float* bx      = (const float*)d_in[6];
    const float* by      = (const float*)d_in[7];
    const float* bz      = (const float*)d_in[8];
    float* out = (float*)d_out;

    // re-zero the output every replay (graph captures this memset node);
    // required because partial sums are atomically accumulated.
    hipMemsetAsync(out, 0, (size_t)out_size * sizeof(float), stream);

    const int threads = NRAY * SPLIT;
    const int block   = 256;
    const int grid    = (threads + block - 1) / block;   // 2032
    drr_kernel<<<grid, block, 0, stream>>>(vol, spacing, sdr, theta, phi, gamma,
                                           bx, by, bz, out);
}

// Round 11
// 56.155 us; speedup vs baseline: 1.0093x; 1.0093x over previous
//
#include <hip/hip_runtime.h>
#include <math.h>

// Keep non-contracted float math in all expressions that feed discrete
// decisions (alpha seeds, voxel trunc) — matches numpy/JAX op-for-op.
#pragma clang fp contract(off)

#define SPLIT 13
#define BATCH 8
static constexpr int HH = 200, WW = 200;
static constexpr int NRAY = HH * WW;

__device__ __forceinline__ float alpha_of(float k, float sp, float src, float sdd) {
    return (k * sp - src) / sdd;   // reference: (k*spacing - src)/sdd, mul-sub-div
}

// Traversal pointer at threshold X: first crossing (traversal order) with
// alpha > X. pos: smallest k, result in [0,257]; neg: largest k, in [-1,256].
// Seeded analytically, fixed up with the exact reference divide (ulp-robust).
__device__ __forceinline__ int seed_ptr(float X, float spv, float sr, float sd, bool pos) {
    const float kf = (X * sd + sr) / spv;
    int kk;
    if (pos) {
        kk = (int)floorf(kf) + 1;
        kk = kk < 0 ? 0 : (kk > 257 ? 257 : kk);
        while (kk > 0    && alpha_of((float)(kk-1), spv, sr, sd) >  X) --kk;
        while (kk <= 256 && alpha_of((float)kk,     spv, sr, sd) <= X) ++kk;
    } else {
        kk = (int)ceilf(kf) - 1;
        kk = kk > 256 ? 256 : (kk < -1 ? -1 : kk);
        while (kk < 256 && alpha_of((float)(kk+1), spv, sr, sd) >  X) ++kk;
        while (kk >= 0  && alpha_of((float)kk,     spv, sr, sd) <= X) --kk;
    }
    return kk;
}

// Generate one interval's (step, byte-offset) from the tM recurrence and
// advance. Identical float ops to rounds 8-10 (bit-identical stream).
#define GEN_INTERVAL(stepv, offv)                                        \
    {   const float q = fminf(fminf(tM0, tM1), tM2);                     \
        stepv = q - prev;                                                \
        const float amid = 0.5f * (prev + q);                            \
        const float p0 = src0 + amid * sdd0;                             \
        const float p1 = src1 + amid * sdd1;                             \
        const float p2 = src2 + amid * sdd2;                             \
        float f0, f1, f2;                                                \
        if (UNIT) { f0 = p0; f1 = p1; f2 = p2; }                         \
        else      { f0 = p0 / spn0; f1 = p1 / spn1; f2 = p2 / spn2; }    \
        f0 = fminf(fmaxf(f0, 0.0f), 255.0f);                             \
        f1 = fminf(fmaxf(f1, 0.0f), 255.0f);                             \
        f2 = fminf(fmaxf(f2, 0.0f), 255.0f);                             \
        const int i0 = (int)f0, i1 = (int)f1, i2 = (int)f2;              \
        offv = (unsigned)(((((255 ^ i0) << 8) + i1) << 8) + i2) << 2;    \
        prev = q;                                                        \
        const bool m0 = (tM0 == q);                                      \
        const bool m1 = !m0 && (tM1 == q);                               \
        const bool m2 = !(m0 || m1);                                     \
        tM0 = m0 ? tM0 + dl0 : tM0;                                      \
        tM1 = m1 ? tM1 + dl1 : tM1;                                      \
        tM2 = m2 ? tM2 + dl2 : tM2; }

// Count-based merge with REAL memory-level parallelism: the 8 loads of a
// batch are issued as volatile inline-asm global_load_dword (the register
// allocator cannot sink/serialize them), then a single counted wait drains
// them before consumption. sched_barrier(0) after the waitcnt keeps the
// consuming fmafs from being scheduled above it (guide rule #18).
template<bool UNIT>
__device__ __forceinline__ float merge_loop(
    const float* __restrict__ vol, int trip, float prev,
    float tM0, float tM1, float tM2,
    float dl0, float dl1, float dl2,
    float src0, float src1, float src2,
    float spn0, float spn1, float spn2,
    float sdd0, float sdd1, float sdd2)
{
    float acc = 0.0f;
    int n = trip;
    while (n >= BATCH) {
        float stepv[BATCH], vox[BATCH];
        unsigned off[BATCH];
        #pragma unroll
        for (int i = 0; i < BATCH; ++i) {
            GEN_INTERVAL(stepv[i], off[i])
            // async gather: dest VGPR written when vmcnt retires, not at issue
            asm volatile("global_load_dword %0, %1, %2"
                         : "=v"(vox[i])
                         : "v"(off[i]), "s"(vol));
        }
        asm volatile("s_waitcnt vmcnt(0)");
        __builtin_amdgcn_sched_barrier(0);   // nothing crosses the wait
        #pragma unroll
        for (int i = 0; i < BATCH; ++i)
            acc = fmaf(stepv[i], vox[i], acc);
        n -= BATCH;
    }
    // serial tail (< BATCH intervals) — plain loads, compiler-managed waits
    while (n > 0) {
        float stepv;
        unsigned off;
        GEN_INTERVAL(stepv, off)
        const float vox = vol[off >> 2];
        acc = fmaf(stepv, vox, acc);
        --n;
    }
    return acc;
}

__global__ __launch_bounds__(256)
void drr_kernel(const float* __restrict__ vol,
                const float* __restrict__ spacing,
                const float* __restrict__ sdrP,
                const float* __restrict__ thetaP,
                const float* __restrict__ phiP,
                const float* __restrict__ gammaP,
                const float* __restrict__ bxP,
                const float* __restrict__ byP,
                const float* __restrict__ bzP,
                float* __restrict__ out)
{
    const int tid = blockIdx.x * blockDim.x + threadIdx.x;
    if (tid >= NRAY * SPLIT) return;          // pad threads exit
    const int seg = tid / NRAY;               // segment in high bits
    const int rid = tid - seg * NRAY;         // lanes = consecutive rid
    const int it  = rid % HH;                 // it fastest -> coalesced i2
    const int is  = rid / HH;

    const float sdr = sdrP[0];
    const float th = thetaP[0], ph = phiP[0], ga = gammaP[0];
    const float ct = cosf(th), st = sinf(th);
    const float cp = cosf(ph), sp = sinf(ph);
    const float cg = cosf(ga), sg = sinf(ga);

    // rotation = Rz @ Ry @ Rx
    const float rot[3][3] = {
        { ct*cp, ct*sp*sg - st*cg, ct*sp*cg + st*sg },
        { st*cp, st*sp*sg + ct*cg, st*sp*cg - ct*sg },
        { -sp,   cp*sg,            cp*cg            }
    };

    float u[3], v[3], source[3], trans[3], src[3], spn[3];
    trans[0] = bxP[0]; trans[1] = byP[0]; trans[2] = bzP[0];
    for (int a = 0; a < 3; ++a) {
        source[a] = sdr * rot[a][0];
        u[a] = (sdr * rot[a][1]) / sdr;
        v[a] = (sdr * rot[a][2]) / sdr;
        src[a] = source[a] + trans[a];
        spn[a] = spacing[a];
    }

    const float tc = (float)(it - HH/2 + 1) * 2.0f;   // DELX
    const float sc = (float)(is - WW/2 + 1) * 2.0f;   // DELY

    float sdd[3];
    float nrm2 = 0.0f;
    for (int a = 0; a < 3; ++a) {
        float tg = tc * u[a] + sc * v[a];
        tg = tg - source[a];     // + center
        tg = tg + trans[a];
        float dd = (tg - src[a]) + 1e-8f;  // sdd = tgt - src + EPS
        sdd[a] = dd;
        nrm2 = nrm2 + dd * dd;
    }
    const bool unit = (spn[0] == 1.0f) & (spn[1] == 1.0f) & (spn[2] == 1.0f);

    float amin = -INFINITY, amax = INFINITY;
    for (int a = 0; a < 3; ++a) {
        float a0 = (0.0f - src[a]) / sdd[a];
        float a1 = (256.0f * spn[a] - src[a]) / sdd[a];
        amin = fmaxf(amin, fminf(a0, a1));
        amax = fminf(amax, fmaxf(a0, a1));
    }

    float acc = 0.0f;
    if (amax > amin) {
        // Segment window (blo, bhi]; identical boundary arithmetic in all segs
        // of a ray, so the windows partition (amin, amax] exactly.
        const float blo = (seg == 0) ? amin
                        : amin + (amax - amin) * ((float)seg / (float)SPLIT);
        const float bhi = (seg == SPLIT - 1) ? amax
                        : amin + (amax - amin) * ((float)(seg + 1) / (float)SPLIT);

        float tM[3], dl[3];
        float prev = -INFINITY;   // largest in-range alpha <= blo
        int trip = 0;

        for (int a = 0; a < 3; ++a) {
            const float sd = sdd[a], sr = src[a], spv = spn[a];
            const bool pos = sd > 0.0f;
            const int ks = seed_ptr(blo, spv, sr, sd, pos);
            const int ke = seed_ptr(bhi, spv, sr, sd, pos);
            int cnt;
            if (pos) {
                cnt = ke - ks;
                if (ks - 1 >= 0) {
                    const float ap = alpha_of((float)(ks-1), spv, sr, sd);
                    if (ap >= amin && ap > prev) prev = ap;
                }
                tM[a] = (ks <= 256) ? alpha_of((float)ks, spv, sr, sd) : INFINITY;
            } else {
                cnt = ks - ke;
                if (ks + 1 <= 256) {
                    const float ap = alpha_of((float)(ks+1), spv, sr, sd);
                    if (ap >= amin && ap > prev) prev = ap;
                }
                tM[a] = (ks >= 0) ? alpha_of((float)ks, spv, sr, sd) : INFINITY;
            }
            if (cnt < 0) cnt = 0;
            trip += cnt;
            dl[a] = fabsf(spv / sd);   // constant alpha increment per crossing
        }

        if (unit) {
            acc = merge_loop<true >(vol, trip, prev,
                                    tM[0], tM[1], tM[2], dl[0], dl[1], dl[2],
                                    src[0], src[1], src[2],
                                    spn[0], spn[1], spn[2],
                                    sdd[0], sdd[1], sdd[2]);
        } else {
            acc = merge_loop<false>(vol, trip, prev,
                                    tM[0], tM[1], tM[2], dl[0], dl[1], dl[2],
                                    src[0], src[1], src[2],
                                    spn[0], spn[1], spn[2],
                                    sdd[0], sdd[1], sdd[2]);
        }
    }

    atomicAdd(&out[it * WW + is], acc * sqrtf(nrm2));
}

extern "C" void kernel_launch(void* const* d_in, const int* in_sizes, int n_in,
                              void* d_out, int out_size, void* d_ws, size_t ws_size,
                              hipStream_t stream)
{
    const float* vol     = (const float*)d_in[0];
    const float* spacing = (const float*)d_in[1];
    const float* sdr     = (const float*)d_in[2];
    const float* theta   = (const float*)d_in[3];
    const float* phi     = (const float*)d_in[4];
    const float* gamma   = (const float*)d_in[5];
    const float* bx      = (const float*)d_in[6];
    const float* by      = (const float*)d_in[7];
    const float* bz      = (const float*)d_in[8];
    float* out = (float*)d_out;

    // re-zero the output every replay (graph captures this memset node);
    // required because partial sums are atomically accumulated.
    hipMemsetAsync(out, 0, (size_t)out_size * sizeof(float), stream);

    const int threads = NRAY * SPLIT;
    const int block   = 256;
    const int grid    = (threads + block - 1) / block;   // 2032
    drr_kernel<<<grid, block, 0, stream>>>(vol, spacing, sdr, theta, phi, gamma,
                                           bx, by, bz, out);
}

// Round 12
// 55.153 us; speedup vs baseline: 1.0276x; 1.0182x over previous
//
#include <hip/hip_runtime.h>
#include <math.h>

// Keep non-contracted float math in all expressions that feed discrete
// decisions (alpha seeds, voxel trunc) — matches numpy/JAX op-for-op.
#pragma clang fp contract(off)

#define SPLIT 13
#define BATCH 8
static constexpr int HH = 200, WW = 200;
static constexpr int NRAY = HH * WW;
static constexpr int RBLK = 157;            // ceil(NRAY/256)
static constexpr int NWG  = RBLK * SPLIT;   // 2041 blocks

__device__ __forceinline__ float alpha_of(float k, float sp, float src, float sdd) {
    return (k * sp - src) / sdd;   // reference: (k*spacing - src)/sdd, mul-sub-div
}

// Traversal pointer at threshold X: first crossing (traversal order) with
// alpha > X. pos: smallest k, result in [0,257]; neg: largest k, in [-1,256].
// Seeded analytically, fixed up with the exact reference divide (ulp-robust).
__device__ __forceinline__ int seed_ptr(float X, float spv, float sr, float sd, bool pos) {
    const float kf = (X * sd + sr) / spv;
    int kk;
    if (pos) {
        kk = (int)floorf(kf) + 1;
        kk = kk < 0 ? 0 : (kk > 257 ? 257 : kk);
        while (kk > 0    && alpha_of((float)(kk-1), spv, sr, sd) >  X) --kk;
        while (kk <= 256 && alpha_of((float)kk,     spv, sr, sd) <= X) ++kk;
    } else {
        kk = (int)ceilf(kf) - 1;
        kk = kk > 256 ? 256 : (kk < -1 ? -1 : kk);
        while (kk < 256 && alpha_of((float)(kk+1), spv, sr, sd) >  X) ++kk;
        while (kk >= 0  && alpha_of((float)kk,     spv, sr, sd) <= X) --kk;
    }
    return kk;
}

// Generate one interval's (step, byte-offset) from the tM recurrence and
// advance. Identical float ops to rounds 8-11 (bit-identical stream).
#define GEN_INTERVAL(stepv, offv)                                        \
    {   const float q = fminf(fminf(tM0, tM1), tM2);                     \
        stepv = q - prev;                                                \
        const float amid = 0.5f * (prev + q);                            \
        const float p0 = src0 + amid * sdd0;                             \
        const float p1 = src1 + amid * sdd1;                             \
        const float p2 = src2 + amid * sdd2;                             \
        float f0, f1, f2;                                                \
        if (UNIT) { f0 = p0; f1 = p1; f2 = p2; }                         \
        else      { f0 = p0 / spn0; f1 = p1 / spn1; f2 = p2 / spn2; }    \
        f0 = fminf(fmaxf(f0, 0.0f), 255.0f);                             \
        f1 = fminf(fmaxf(f1, 0.0f), 255.0f);                             \
        f2 = fminf(fmaxf(f2, 0.0f), 255.0f);                             \
        const int i0 = (int)f0, i1 = (int)f1, i2 = (int)f2;              \
        offv = (unsigned)(((((255 ^ i0) << 8) + i1) << 8) + i2) << 2;    \
        prev = q;                                                        \
        const bool m0 = (tM0 == q);                                      \
        const bool m1 = !m0 && (tM1 == q);                               \
        const bool m2 = !(m0 || m1);                                     \
        tM0 = m0 ? tM0 + dl0 : tM0;                                      \
        tM1 = m1 ? tM1 + dl1 : tM1;                                      \
        tM2 = m2 ? tM2 + dl2 : tM2; }

// Count-based merge with guaranteed MLP: the 8 loads of a batch are issued as
// volatile inline-asm global_load_dword, drained by one counted wait before
// consumption; sched_barrier(0) keeps the fmafs below the wait (rule #18).
template<bool UNIT>
__device__ __forceinline__ float merge_loop(
    const float* __restrict__ vol, int trip, float prev,
    float tM0, float tM1, float tM2,
    float dl0, float dl1, float dl2,
    float src0, float src1, float src2,
    float spn0, float spn1, float spn2,
    float sdd0, float sdd1, float sdd2)
{
    float acc = 0.0f;
    int n = trip;
    while (n >= BATCH) {
        float stepv[BATCH], vox[BATCH];
        unsigned off[BATCH];
        #pragma unroll
        for (int i = 0; i < BATCH; ++i) {
            GEN_INTERVAL(stepv[i], off[i])
            asm volatile("global_load_dword %0, %1, %2"
                         : "=v"(vox[i])
                         : "v"(off[i]), "s"(vol));
        }
        asm volatile("s_waitcnt vmcnt(0)");
        __builtin_amdgcn_sched_barrier(0);
        #pragma unroll
        for (int i = 0; i < BATCH; ++i)
            acc = fmaf(stepv[i], vox[i], acc);
        n -= BATCH;
    }
    while (n > 0) {
        float stepv;
        unsigned off;
        GEN_INTERVAL(stepv, off)
        const float vox = vol[off >> 2];
        acc = fmaf(stepv, vox, acc);
        --n;
    }
    return acc;
}

__global__ __launch_bounds__(256)
void drr_kernel(const float* __restrict__ vol,
                const float* __restrict__ spacing,
                const float* __restrict__ sdrP,
                const float* __restrict__ thetaP,
                const float* __restrict__ phiP,
                const float* __restrict__ gammaP,
                const float* __restrict__ bxP,
                const float* __restrict__ byP,
                const float* __restrict__ bzP,
                float* __restrict__ out)
{
    // --- XCD-aware bijective block swizzle (T1, m204 chunked) -------------
    // NWG = 2041 blocks; q = 255, r = 1: xcd 0 gets 256 slots, xcd 1..7 get
    // 255 each. Consecutive swz within an XCD chunk are seg-fastest, so each
    // XCD owns ~20 consecutive rid-blocks (a ~25-row is-band = one y-slab of
    // the volume) across ALL segments -> per-XCD L2 working set ~5x smaller.
    const int lin = blockIdx.x;
    const int xcd = lin & 7;
    const int pos = lin >> 3;
    const int swz = (xcd == 0) ? pos : (256 + (xcd - 1) * 255 + pos);
    const int ridBlk = swz / SPLIT;
    const int seg    = swz - ridBlk * SPLIT;

    const int rid = ridBlk * 256 + threadIdx.x;   // lanes = consecutive rid
    if (rid >= NRAY) return;
    const int it  = rid % HH;                 // it fastest -> coalesced i2
    const int is  = rid / HH;

    const float sdr = sdrP[0];
    const float th = thetaP[0], ph = phiP[0], ga = gammaP[0];
    const float ct = cosf(th), st = sinf(th);
    const float cp = cosf(ph), sp = sinf(ph);
    const float cg = cosf(ga), sg = sinf(ga);

    // rotation = Rz @ Ry @ Rx
    const float rot[3][3] = {
        { ct*cp, ct*sp*sg - st*cg, ct*sp*cg + st*sg },
        { st*cp, st*sp*sg + ct*cg, st*sp*cg - ct*sg },
        { -sp,   cp*sg,            cp*cg            }
    };

    float u[3], v[3], source[3], trans[3], src[3], spn[3];
    trans[0] = bxP[0]; trans[1] = byP[0]; trans[2] = bzP[0];
    for (int a = 0; a < 3; ++a) {
        source[a] = sdr * rot[a][0];
        u[a] = (sdr * rot[a][1]) / sdr;
        v[a] = (sdr * rot[a][2]) / sdr;
        src[a] = source[a] + trans[a];
        spn[a] = spacing[a];
    }

    const float tc = (float)(it - HH/2 + 1) * 2.0f;   // DELX
    const float sc = (float)(is - WW/2 + 1) * 2.0f;   // DELY

    float sdd[3];
    float nrm2 = 0.0f;
    for (int a = 0; a < 3; ++a) {
        float tg = tc * u[a] + sc * v[a];
        tg = tg - source[a];     // + center
        tg = tg + trans[a];
        float dd = (tg - src[a]) + 1e-8f;  // sdd = tgt - src + EPS
        sdd[a] = dd;
        nrm2 = nrm2 + dd * dd;
    }
    const bool unit = (spn[0] == 1.0f) & (spn[1] == 1.0f) & (spn[2] == 1.0f);

    float amin = -INFINITY, amax = INFINITY;
    for (int a = 0; a < 3; ++a) {
        float a0 = (0.0f - src[a]) / sdd[a];
        float a1 = (256.0f * spn[a] - src[a]) / sdd[a];
        amin = fmaxf(amin, fminf(a0, a1));
        amax = fminf(amax, fmaxf(a0, a1));
    }

    float acc = 0.0f;
    if (amax > amin) {
        // Segment window (blo, bhi]; identical boundary arithmetic in all segs
        // of a ray, so the windows partition (amin, amax] exactly.
        const float blo = (seg == 0) ? amin
                        : amin + (amax - amin) * ((float)seg / (float)SPLIT);
        const float bhi = (seg == SPLIT - 1) ? amax
                        : amin + (amax - amin) * ((float)(seg + 1) / (float)SPLIT);

        float tM[3], dl[3];
        float prev = -INFINITY;   // largest in-range alpha <= blo
        int trip = 0;

        for (int a = 0; a < 3; ++a) {
            const float sd = sdd[a], sr = src[a], spv = spn[a];
            const bool pos2 = sd > 0.0f;
            const int ks = seed_ptr(blo, spv, sr, sd, pos2);
            const int ke = seed_ptr(bhi, spv, sr, sd, pos2);
            int cnt;
            if (pos2) {
                cnt = ke - ks;
                if (ks - 1 >= 0) {
                    const float ap = alpha_of((float)(ks-1), spv, sr, sd);
                    if (ap >= amin && ap > prev) prev = ap;
                }
                tM[a] = (ks <= 256) ? alpha_of((float)ks, spv, sr, sd) : INFINITY;
            } else {
                cnt = ks - ke;
                if (ks + 1 <= 256) {
                    const float ap = alpha_of((float)(ks+1), spv, sr, sd);
                    if (ap >= amin && ap > prev) prev = ap;
                }
                tM[a] = (ks >= 0) ? alpha_of((float)ks, spv, sr, sd) : INFINITY;
            }
            if (cnt < 0) cnt = 0;
            trip += cnt;
            dl[a] = fabsf(spv / sd);   // constant alpha increment per crossing
        }

        if (unit) {
            acc = merge_loop<true >(vol, trip, prev,
                                    tM[0], tM[1], tM[2], dl[0], dl[1], dl[2],
                                    src[0], src[1], src[2],
                                    spn[0], spn[1], spn[2],
                                    sdd[0], sdd[1], sdd[2]);
        } else {
            acc = merge_loop<false>(vol, trip, prev,
                                    tM[0], tM[1], tM[2], dl[0], dl[1], dl[2],
                                    src[0], src[1], src[2],
                                    spn[0], spn[1], spn[2],
                                    sdd[0], sdd[1], sdd[2]);
        }
    }

    atomicAdd(&out[it * WW + is], acc * sqrtf(nrm2));
}

extern "C" void kernel_launch(void* const* d_in, const int* in_sizes, int n_in,
                              void* d_out, int out_size, void* d_ws, size_t ws_size,
                              hipStream_t stream)
{
    const float* vol     = (const float*)d_in[0];
    const float* spacing = (const float*)d_in[1];
    const float* sdr     = (const float*)d_in[2];
    const float* theta   = (const float*)d_in[3];
    const float* phi     = (const float*)d_in[4];
    const float* gamma   = (const float*)d_in[5];
    const float* bx      = (const float*)d_in[6];
    const float* by      = (const float*)d_in[7];
    const float* bz      = (const float*)d_in[8];
    float* out = (float*)d_out;

    // re-zero the output every replay (graph captures this memset node);
    // required because partial sums are atomically accumulated.
    hipMemsetAsync(out, 0, (size_t)out_size * sizeof(float), stream);

    drr_kernel<<<NWG, 256, 0, stream>>>(vol, spacing, sdr, theta, phi, gamma,
                                        bx, by, bz, out);
}

// Round 13
// 52.622 us; speedup vs baseline: 1.0771x; 1.0481x over previous
//
#include <hip/hip_runtime.h>
#include <math.h>

// Keep non-contracted float math in all expressions that feed discrete
// decisions (alpha seeds, voxel trunc) — matches numpy/JAX op-for-op.
#pragma clang fp contract(off)

#define SPLIT 13
#define BATCH 8
static constexpr int HH = 200, WW = 200;
static constexpr int NRAY = HH * WW;
static constexpr int RBLK = 157;            // ceil(NRAY/256)
static constexpr int NWG  = RBLK * SPLIT;   // 2041 blocks

// d_ws float layout
static constexpr int WS_SDD0 = 0;
static constexpr int WS_SDD1 = NRAY;
static constexpr int WS_SDD2 = 2 * NRAY;
static constexpr int WS_AMIN = 3 * NRAY;
static constexpr int WS_AMAX = 4 * NRAY;
static constexpr int WS_NORM = 5 * NRAY;
static constexpr int WS_UNI  = 6 * NRAY;          // src0..2, spn0..2
static constexpr int WS_PART = 6 * NRAY + 8;      // SPLIT x NRAY partials
static constexpr size_t WS_BYTES = (size_t)(WS_PART + SPLIT * NRAY) * 4;

__device__ __forceinline__ float alpha_of(float k, float sp, float src, float sdd) {
    return (k * sp - src) / sdd;   // reference: (k*spacing - src)/sdd, mul-sub-div
}

// Traversal pointer at threshold X: first crossing (traversal order) with
// alpha > X. Seeded analytically, fixed up with the exact reference divide.
__device__ __forceinline__ int seed_ptr(float X, float spv, float sr, float sd, bool pos) {
    const float kf = (X * sd + sr) / spv;
    int kk;
    if (pos) {
        kk = (int)floorf(kf) + 1;
        kk = kk < 0 ? 0 : (kk > 257 ? 257 : kk);
        while (kk > 0    && alpha_of((float)(kk-1), spv, sr, sd) >  X) --kk;
        while (kk <= 256 && alpha_of((float)kk,     spv, sr, sd) <= X) ++kk;
    } else {
        kk = (int)ceilf(kf) - 1;
        kk = kk > 256 ? 256 : (kk < -1 ? -1 : kk);
        while (kk < 256 && alpha_of((float)(kk+1), spv, sr, sd) >  X) ++kk;
        while (kk >= 0  && alpha_of((float)kk,     spv, sr, sd) <= X) --kk;
    }
    return kk;
}

// Generate one interval's (step, byte-offset) from the tM recurrence and
// advance. Identical float ops to rounds 8-12 (bit-identical stream).
#define GEN_INTERVAL(stepv, offv)                                        \
    {   const float q = fminf(fminf(tM0, tM1), tM2);                     \
        stepv = q - prev;                                                \
        const float amid = 0.5f * (prev + q);                            \
        const float p0 = src0 + amid * sdd0;                             \
        const float p1 = src1 + amid * sdd1;                             \
        const float p2 = src2 + amid * sdd2;                             \
        float f0, f1, f2;                                                \
        if (UNIT) { f0 = p0; f1 = p1; f2 = p2; }                         \
        else      { f0 = p0 / spn0; f1 = p1 / spn1; f2 = p2 / spn2; }    \
        f0 = fminf(fmaxf(f0, 0.0f), 255.0f);                             \
        f1 = fminf(fmaxf(f1, 0.0f), 255.0f);                             \
        f2 = fminf(fmaxf(f2, 0.0f), 255.0f);                             \
        const int i0 = (int)f0, i1 = (int)f1, i2 = (int)f2;              \
        offv = (unsigned)(((((255 ^ i0) << 8) + i1) << 8) + i2) << 2;    \
        prev = q;                                                        \
        const bool m0 = (tM0 == q);                                      \
        const bool m1 = !m0 && (tM1 == q);                               \
        const bool m2 = !(m0 || m1);                                     \
        tM0 = m0 ? tM0 + dl0 : tM0;                                      \
        tM1 = m1 ? tM1 + dl1 : tM1;                                      \
        tM2 = m2 ? tM2 + dl2 : tM2; }

// Count-based merge with guaranteed MLP (volatile asm loads + counted wait).
template<bool UNIT>
__device__ __forceinline__ float merge_loop(
    const float* __restrict__ vol, int trip, float prev,
    float tM0, float tM1, float tM2,
    float dl0, float dl1, float dl2,
    float src0, float src1, float src2,
    float spn0, float spn1, float spn2,
    float sdd0, float sdd1, float sdd2)
{
    float acc = 0.0f;
    int n = trip;
    while (n >= BATCH) {
        float stepv[BATCH], vox[BATCH];
        unsigned off[BATCH];
        #pragma unroll
        for (int i = 0; i < BATCH; ++i) {
            GEN_INTERVAL(stepv[i], off[i])
            asm volatile("global_load_dword %0, %1, %2"
                         : "=v"(vox[i])
                         : "v"(off[i]), "s"(vol));
        }
        asm volatile("s_waitcnt vmcnt(0)");
        __builtin_amdgcn_sched_barrier(0);
        #pragma unroll
        for (int i = 0; i < BATCH; ++i)
            acc = fmaf(stepv[i], vox[i], acc);
        n -= BATCH;
    }
    while (n > 0) {
        float stepv;
        unsigned off;
        GEN_INTERVAL(stepv, off)
        const float vox = vol[off >> 2];
        acc = fmaf(stepv, vox, acc);
        --n;
    }
    return acc;
}

// ---------------- A: per-ray geometry (exactly the old per-thread setup) ----
__global__ __launch_bounds__(256)
void drr_pre(const float* __restrict__ spacing,
             const float* __restrict__ sdrP,  const float* __restrict__ thetaP,
             const float* __restrict__ phiP,  const float* __restrict__ gammaP,
             const float* __restrict__ bxP,   const float* __restrict__ byP,
             const float* __restrict__ bzP,   float* __restrict__ ws)
{
    const int rid = blockIdx.x * blockDim.x + threadIdx.x;
    if (rid >= NRAY) return;
    const int it = rid % HH, is = rid / HH;

    const float sdr = sdrP[0];
    const float th = thetaP[0], ph = phiP[0], ga = gammaP[0];
    const float ct = cosf(th), st = sinf(th);
    const float cp = cosf(ph), sp = sinf(ph);
    const float cg = cosf(ga), sg = sinf(ga);

    const float rot[3][3] = {
        { ct*cp, ct*sp*sg - st*cg, ct*sp*cg + st*sg },
        { st*cp, st*sp*sg + ct*cg, st*sp*cg - ct*sg },
        { -sp,   cp*sg,            cp*cg            }
    };

    float u[3], v[3], source[3], trans[3], src[3], spn[3];
    trans[0] = bxP[0]; trans[1] = byP[0]; trans[2] = bzP[0];
    for (int a = 0; a < 3; ++a) {
        source[a] = sdr * rot[a][0];
        u[a] = (sdr * rot[a][1]) / sdr;
        v[a] = (sdr * rot[a][2]) / sdr;
        src[a] = source[a] + trans[a];
        spn[a] = spacing[a];
    }

    const float tc = (float)(it - HH/2 + 1) * 2.0f;   // DELX
    const float sc = (float)(is - WW/2 + 1) * 2.0f;   // DELY

    float sdd[3];
    float nrm2 = 0.0f;
    for (int a = 0; a < 3; ++a) {
        float tg = tc * u[a] + sc * v[a];
        tg = tg - source[a];     // + center
        tg = tg + trans[a];
        float dd = (tg - src[a]) + 1e-8f;  // sdd = tgt - src + EPS
        sdd[a] = dd;
        nrm2 = nrm2 + dd * dd;
    }

    float amin = -INFINITY, amax = INFINITY;
    for (int a = 0; a < 3; ++a) {
        float a0 = (0.0f - src[a]) / sdd[a];
        float a1 = (256.0f * spn[a] - src[a]) / sdd[a];
        amin = fmaxf(amin, fminf(a0, a1));
        amax = fminf(amax, fmaxf(a0, a1));
    }

    ws[WS_SDD0 + rid] = sdd[0];
    ws[WS_SDD1 + rid] = sdd[1];
    ws[WS_SDD2 + rid] = sdd[2];
    ws[WS_AMIN + rid] = amin;
    ws[WS_AMAX + rid] = amax;
    ws[WS_NORM + rid] = sqrtf(nrm2);
    if (rid == 0) {   // src and spn are ray-independent
        ws[WS_UNI + 0] = src[0]; ws[WS_UNI + 1] = src[1]; ws[WS_UNI + 2] = src[2];
        ws[WS_UNI + 3] = spn[0]; ws[WS_UNI + 4] = spn[1]; ws[WS_UNI + 5] = spn[2];
    }
}

// ---------------- B: merge (per-thread setup gone; no atomics) --------------
__global__ __launch_bounds__(256)
void drr_main(const float* __restrict__ vol,
              float* __restrict__ ws)
{
    // XCD-aware bijective swizzle (unchanged from round 12)
    const int lin = blockIdx.x;
    const int xcd = lin & 7;
    const int pos = lin >> 3;
    const int swz = (xcd == 0) ? pos : (256 + (xcd - 1) * 255 + pos);
    const int ridBlk = swz / SPLIT;
    const int seg    = swz - ridBlk * SPLIT;

    const int rid = ridBlk * 256 + threadIdx.x;
    if (rid >= NRAY) return;

    const float sdd0 = ws[WS_SDD0 + rid];
    const float sdd1 = ws[WS_SDD1 + rid];
    const float sdd2 = ws[WS_SDD2 + rid];
    const float amin = ws[WS_AMIN + rid];
    const float amax = ws[WS_AMAX + rid];
    const float src0 = ws[WS_UNI + 0], src1 = ws[WS_UNI + 1], src2 = ws[WS_UNI + 2];
    const float spn0 = ws[WS_UNI + 3], spn1 = ws[WS_UNI + 4], spn2 = ws[WS_UNI + 5];
    const bool unit = (spn0 == 1.0f) & (spn1 == 1.0f) & (spn2 == 1.0f);

    float acc = 0.0f;
    if (amax > amin) {
        const float blo = (seg == 0) ? amin
                        : amin + (amax - amin) * ((float)seg / (float)SPLIT);
        const float bhi = (seg == SPLIT - 1) ? amax
                        : amin + (amax - amin) * ((float)(seg + 1) / (float)SPLIT);

        const float sddv[3] = { sdd0, sdd1, sdd2 };
        const float srcv[3] = { src0, src1, src2 };
        const float spnv[3] = { spn0, spn1, spn2 };
        float tM[3], dl[3];
        float prev = -INFINITY;
        int trip = 0;

        for (int a = 0; a < 3; ++a) {
            const float sd = sddv[a], sr = srcv[a], spv = spnv[a];
            const bool pos2 = sd > 0.0f;
            const int ks = seed_ptr(blo, spv, sr, sd, pos2);
            const int ke = seed_ptr(bhi, spv, sr, sd, pos2);
            int cnt;
            if (pos2) {
                cnt = ke - ks;
                if (ks - 1 >= 0) {
                    const float ap = alpha_of((float)(ks-1), spv, sr, sd);
                    if (ap >= amin && ap > prev) prev = ap;
                }
                tM[a] = (ks <= 256) ? alpha_of((float)ks, spv, sr, sd) : INFINITY;
            } else {
                cnt = ks - ke;
                if (ks + 1 <= 256) {
                    const float ap = alpha_of((float)(ks+1), spv, sr, sd);
                    if (ap >= amin && ap > prev) prev = ap;
                }
                tM[a] = (ks >= 0) ? alpha_of((float)ks, spv, sr, sd) : INFINITY;
            }
            if (cnt < 0) cnt = 0;
            trip += cnt;
            dl[a] = fabsf(spv / sd);
        }

        if (unit) {
            acc = merge_loop<true >(vol, trip, prev, tM[0], tM[1], tM[2],
                                    dl[0], dl[1], dl[2], src0, src1, src2,
                                    spn0, spn1, spn2, sdd0, sdd1, sdd2);
        } else {
            acc = merge_loop<false>(vol, trip, prev, tM[0], tM[1], tM[2],
                                    dl[0], dl[1], dl[2], src0, src1, src2,
                                    spn0, spn1, spn2, sdd0, sdd1, sdd2);
        }
    }

    // plain coalesced store — no atomic, no memset dependency
    ws[WS_PART + seg * NRAY + rid] = acc;
}

// ---------------- C: reduce partials, apply norm, write out ----------------
__global__ __launch_bounds__(256)
void drr_fin(const float* __restrict__ ws, float* __restrict__ out)
{
    const int rid = blockIdx.x * blockDim.x + threadIdx.x;
    if (rid >= NRAY) return;
    float s = 0.0f;
    #pragma unroll
    for (int seg = 0; seg < SPLIT; ++seg)
        s = s + ws[WS_PART + seg * NRAY + rid];   // fixed seg order
    const int it = rid % HH, is = rid / HH;
    out[it * WW + is] = s * ws[WS_NORM + rid];
}

// ---------------- fallback: round-12 monolithic atomic path ----------------
__global__ __launch_bounds__(256)
void drr_mono(const float* __restrict__ vol,
              const float* __restrict__ spacing,
              const float* __restrict__ sdrP,  const float* __restrict__ thetaP,
              const float* __restrict__ phiP,  const float* __restrict__ gammaP,
              const float* __restrict__ bxP,   const float* __restrict__ byP,
              const float* __restrict__ bzP,   float* __restrict__ out)
{
    const int lin = blockIdx.x;
    const int xcd = lin & 7;
    const int pos = lin >> 3;
    const int swz = (xcd == 0) ? pos : (256 + (xcd - 1) * 255 + pos);
    const int ridBlk = swz / SPLIT;
    const int seg    = swz - ridBlk * SPLIT;
    const int rid = ridBlk * 256 + threadIdx.x;
    if (rid >= NRAY) return;
    const int it = rid % HH, is = rid / HH;

    const float sdr = sdrP[0];
    const float th = thetaP[0], ph = phiP[0], ga = gammaP[0];
    const float ct = cosf(th), st = sinf(th);
    const float cp = cosf(ph), sp = sinf(ph);
    const float cg = cosf(ga), sg = sinf(ga);
    const float rot[3][3] = {
        { ct*cp, ct*sp*sg - st*cg, ct*sp*cg + st*sg },
        { st*cp, st*sp*sg + ct*cg, st*sp*cg - ct*sg },
        { -sp,   cp*sg,            cp*cg            }
    };
    float u[3], v[3], source[3], trans[3], src[3], spn[3];
    trans[0] = bxP[0]; trans[1] = byP[0]; trans[2] = bzP[0];
    for (int a = 0; a < 3; ++a) {
        source[a] = sdr * rot[a][0];
        u[a] = (sdr * rot[a][1]) / sdr;
        v[a] = (sdr * rot[a][2]) / sdr;
        src[a] = source[a] + trans[a];
        spn[a] = spacing[a];
    }
    const float tc = (float)(it - HH/2 + 1) * 2.0f;
    const float sc = (float)(is - WW/2 + 1) * 2.0f;
    float sdd[3]; float nrm2 = 0.0f;
    for (int a = 0; a < 3; ++a) {
        float tg = tc * u[a] + sc * v[a];
        tg = tg - source[a];
        tg = tg + trans[a];
        float dd = (tg - src[a]) + 1e-8f;
        sdd[a] = dd;
        nrm2 = nrm2 + dd * dd;
    }
    const bool unit = (spn[0] == 1.0f) & (spn[1] == 1.0f) & (spn[2] == 1.0f);
    float amin = -INFINITY, amax = INFINITY;
    for (int a = 0; a < 3; ++a) {
        float a0 = (0.0f - src[a]) / sdd[a];
        float a1 = (256.0f * spn[a] - src[a]) / sdd[a];
        amin = fmaxf(amin, fminf(a0, a1));
        amax = fminf(amax, fmaxf(a0, a1));
    }
    float acc = 0.0f;
    if (amax > amin) {
        const float blo = (seg == 0) ? amin
                        : amin + (amax - amin) * ((float)seg / (float)SPLIT);
        const float bhi = (seg == SPLIT - 1) ? amax
                        : amin + (amax - amin) * ((float)(seg + 1) / (float)SPLIT);
        float tM[3], dl[3];
        float prev = -INFINITY;
        int trip = 0;
        for (int a = 0; a < 3; ++a) {
            const float sd = sdd[a], sr = src[a], spv = spn[a];
            const bool pos2 = sd > 0.0f;
            const int ks = seed_ptr(blo, spv, sr, sd, pos2);
            const int ke = seed_ptr(bhi, spv, sr, sd, pos2);
            int cnt;
            if (pos2) {
                cnt = ke - ks;
                if (ks - 1 >= 0) {
                    const float ap = alpha_of((float)(ks-1), spv, sr, sd);
                    if (ap >= amin && ap > prev) prev = ap;
                }
                tM[a] = (ks <= 256) ? alpha_of((float)ks, spv, sr, sd) : INFINITY;
            } else {
                cnt = ks - ke;
                if (ks + 1 <= 256) {
                    const float ap = alpha_of((float)(ks+1), spv, sr, sd);
                    if (ap >= amin && ap > prev) prev = ap;
                }
                tM[a] = (ks >= 0) ? alpha_of((float)ks, spv, sr, sd) : INFINITY;
            }
            if (cnt < 0) cnt = 0;
            trip += cnt;
            dl[a] = fabsf(spv / sd);
        }
        if (unit) {
            acc = merge_loop<true >(vol, trip, prev, tM[0], tM[1], tM[2],
                                    dl[0], dl[1], dl[2], src[0], src[1], src[2],
                                    spn[0], spn[1], spn[2], sdd[0], sdd[1], sdd[2]);
        } else {
            acc = merge_loop<false>(vol, trip, prev, tM[0], tM[1], tM[2],
                                    dl[0], dl[1], dl[2], src[0], src[1], src[2],
                                    spn[0], spn[1], spn[2], sdd[0], sdd[1], sdd[2]);
        }
    }
    atomicAdd(&out[it * WW + is], acc * sqrtf(nrm2));
}

extern "C" void kernel_launch(void* const* d_in, const int* in_sizes, int n_in,
                              void* d_out, int out_size, void* d_ws, size_t ws_size,
                              hipStream_t stream)
{
    const float* vol     = (const float*)d_in[0];
    const float* spacing = (const float*)d_in[1];
    const float* sdr     = (const float*)d_in[2];
    const float* theta   = (const float*)d_in[3];
    const float* phi     = (const float*)d_in[4];
    const float* gamma   = (const float*)d_in[5];
    const float* bx      = (const float*)d_in[6];
    const float* by      = (const float*)d_in[7];
    const float* bz      = (const float*)d_in[8];
    float* out = (float*)d_out;

    if (ws_size >= WS_BYTES) {
        float* ws = (float*)d_ws;
        drr_pre<<<RBLK, 256, 0, stream>>>(spacing, sdr, theta, phi, gamma,
                                          bx, by, bz, ws);
        drr_main<<<NWG, 256, 0, stream>>>(vol, ws);
        drr_fin<<<RBLK, 256, 0, stream>>>(ws, out);
    } else {
        hipMemsetAsync(out, 0, (size_t)out_size * sizeof(float), stream);
        drr_mono<<<NWG, 256, 0, stream>>>(vol, spacing, sdr, theta, phi, gamma,
                                          bx, by, bz, out);
    }
}